// Round 5
// baseline (2432.703 us; speedup 1.0000x reference)
//
#include <hip/hip_runtime.h>
#include <hip/hip_bf16.h>
#include <cmath>

#define BATCH 8
#define CIN 64
#define COUT 128
#define NPTS 16384
#define RES 32
#define R3 32768
#define NGROUP 8
#define GSIZE 16

typedef __hip_bfloat16 bf16;
typedef __attribute__((ext_vector_type(8))) short short8;
typedef __attribute__((ext_vector_type(4))) float f32x4;

__device__ inline float b2f(ushort u) { union { float f; uint v; } x; x.v = ((uint)u) << 16; return x.f; }
__device__ inline ushort f2bu(float f) { __hip_bfloat16 h = __float2bfloat16(f); return *reinterpret_cast<ushort*>(&h); }

// ---------------- coord stats ----------------
__global__ __launch_bounds__(256) void coord_stats_k(const float* __restrict__ coords,
                                                     float* __restrict__ bstats) {
    int b = blockIdx.x;
    int t = threadIdx.x;
    __shared__ float red[256];
    __shared__ float means[3];
    for (int c = 0; c < 3; ++c) {
        float acc = 0.f;
        const float* p = coords + ((size_t)b * 3 + c) * NPTS;
        for (int n = t; n < NPTS; n += 256) acc += p[n];
        red[t] = acc; __syncthreads();
        for (int s = 128; s > 0; s >>= 1) { if (t < s) red[t] += red[t + s]; __syncthreads(); }
        if (t == 0) means[c] = red[0] * (1.f / NPTS);
        __syncthreads();
    }
    float m0 = means[0], m1 = means[1], m2 = means[2];
    const float* px = coords + ((size_t)b * 3 + 0) * NPTS;
    const float* py = coords + ((size_t)b * 3 + 1) * NPTS;
    const float* pz = coords + ((size_t)b * 3 + 2) * NPTS;
    float mx = 0.f;
    for (int n = t; n < NPTS; n += 256) {
        float dx = px[n] - m0, dy = py[n] - m1, dz = pz[n] - m2;
        mx = fmaxf(mx, sqrtf(dx * dx + dy * dy + dz * dz));
    }
    red[t] = mx; __syncthreads();
    for (int s = 128; s > 0; s >>= 1) { if (t < s) red[t] = fmaxf(red[t], red[t + s]); __syncthreads(); }
    if (t == 0) {
        bstats[b * 4 + 0] = m0; bstats[b * 4 + 1] = m1; bstats[b * 4 + 2] = m2;
        bstats[b * 4 + 3] = 1.f / (2.f * red[0]);
    }
}

// ---------------- per-point voxel index + nc + count ----------------
__global__ __launch_bounds__(256) void vox_idx_k(const float* __restrict__ coords,
                                                 const float* __restrict__ bstats,
                                                 float* __restrict__ nc,
                                                 int* __restrict__ vidx,
                                                 int* __restrict__ slot,
                                                 unsigned int* __restrict__ cnts) {
    int g = blockIdx.x * 256 + threadIdx.x;
    int b = g >> 14, n = g & (NPTS - 1);
    float m0 = bstats[b * 4 + 0], m1 = bstats[b * 4 + 1], m2 = bstats[b * 4 + 2];
    float sc = bstats[b * 4 + 3];
    float x = coords[((size_t)b * 3 + 0) * NPTS + n];
    float y = coords[((size_t)b * 3 + 1) * NPTS + n];
    float z = coords[((size_t)b * 3 + 2) * NPTS + n];
    float ncx = fminf(fmaxf(((x - m0) * sc + 0.5f) * (float)RES, 0.f), RES - 1.f);
    float ncy = fminf(fmaxf(((y - m1) * sc + 0.5f) * (float)RES, 0.f), RES - 1.f);
    float ncz = fminf(fmaxf(((z - m2) * sc + 0.5f) * (float)RES, 0.f), RES - 1.f);
    nc[((size_t)b * 3 + 0) * NPTS + n] = ncx;
    nc[((size_t)b * 3 + 1) * NPTS + n] = ncy;
    nc[((size_t)b * 3 + 2) * NPTS + n] = ncz;
    int ix = min(max((int)rintf(ncx), 0), RES - 1);  // rintf = half-even = jnp.round
    int iy = min(max((int)rintf(ncy), 0), RES - 1);
    int iz = min(max((int)rintf(ncz), 0), RES - 1);
    int v = b * R3 + (ix * RES + iy) * RES + iz;
    vidx[g] = v;
    slot[g] = (int)atomicAdd(&cnts[v], 1u);
}

// ---------------- feature transpose: [b][64][N] fp32 -> [b][n][64] fp32 ----------------
__global__ __launch_bounds__(256) void transpose_feats_k(const float* __restrict__ feats,
                                                         float* __restrict__ featT) {
    int blk = blockIdx.x;
    int b = blk >> 8, ntile = blk & 255;
    int t = threadIdx.x;
    __shared__ float lds[64][65];
    for (int e = t; e < 64 * 64; e += 256) {
        int c = e >> 6, n = e & 63;
        lds[c][n] = feats[((size_t)b * CIN + c) * NPTS + ntile * 64 + n];
    }
    __syncthreads();
    for (int e = t; e < 64 * 64; e += 256) {
        int n = e >> 6, c = e & 63;
        featT[(((size_t)b << 14) + ntile * 64 + n) * CIN + c] = lds[c][n];
    }
}

// ---------------- scan ----------------
__global__ __launch_bounds__(256) void scan1_k(const unsigned int* __restrict__ cnts,
                                               unsigned int* __restrict__ offs,
                                               unsigned int* __restrict__ part) {
    int t = threadIdx.x;
    int g = blockIdx.x * 256 + t;
    unsigned int v = cnts[g];
    __shared__ unsigned int s[256];
    s[t] = v; __syncthreads();
    for (int d = 1; d < 256; d <<= 1) {
        unsigned int x = (t >= d) ? s[t - d] : 0u;
        __syncthreads();
        s[t] += x;
        __syncthreads();
    }
    offs[g] = s[t] - v;
    if (t == 255) part[blockIdx.x] = s[255];
}

__global__ __launch_bounds__(1024) void scan2_k(unsigned int* __restrict__ part) {
    int t = threadIdx.x;
    unsigned int v = part[t];
    __shared__ unsigned int s[1024];
    s[t] = v; __syncthreads();
    for (int d = 1; d < 1024; d <<= 1) {
        unsigned int x = (t >= d) ? s[t - d] : 0u;
        __syncthreads();
        s[t] += x;
        __syncthreads();
    }
    part[t] = s[t] - v;
}

__global__ __launch_bounds__(256) void scan3_k(unsigned int* __restrict__ offs,
                                               const unsigned int* __restrict__ part) {
    int g = blockIdx.x * 256 + threadIdx.x;
    offs[g] += part[blockIdx.x];
}

// ---------------- scatter point ids into CSR ----------------
__global__ __launch_bounds__(256) void scatter_pts_k(const int* __restrict__ vidx,
                                                     const int* __restrict__ slot,
                                                     const unsigned int* __restrict__ offs,
                                                     unsigned int* __restrict__ pidx) {
    int g = blockIdx.x * 256 + threadIdx.x;
    int n = g & (NPTS - 1);
    int v = vidx[g];
    pidx[offs[v] + slot[g]] = (unsigned int)n;
}

// ---------------- gather: CSR mean -> bf16 channel-last vox ----------------
__global__ __launch_bounds__(256) void gather_k(const float* __restrict__ featT,
                                                const unsigned int* __restrict__ cnts,
                                                const unsigned int* __restrict__ offs,
                                                const unsigned int* __restrict__ pidx,
                                                bf16* __restrict__ voxCL) {
    int u = blockIdx.x * 256 + threadIdx.x;
    int v = u >> 3;
    int l8 = u & 7;
    int b = v >> 15;
    unsigned int cnt = cnts[v];
    unsigned int off = offs[v];
    float acc[8] = {0.f, 0.f, 0.f, 0.f, 0.f, 0.f, 0.f, 0.f};
    for (unsigned int i = 0; i < cnt; ++i) {
        unsigned int n = pidx[off + i];
        const float4* fp = (const float4*)(featT + (((size_t)b << 14) + n) * CIN + l8 * 8);
        float4 f0 = fp[0], f1 = fp[1];
        acc[0] += f0.x; acc[1] += f0.y; acc[2] += f0.z; acc[3] += f0.w;
        acc[4] += f1.x; acc[5] += f1.y; acc[6] += f1.z; acc[7] += f1.w;
    }
    float inv = 1.f / fmaxf((float)cnt, 1.f);
    ushort o[8];
#pragma unroll
    for (int j = 0; j < 8; ++j) o[j] = f2bu(acc[j] * inv);
    *(short8*)(voxCL + (size_t)v * CIN + l8 * 8) = *(short8*)o;
}

// ---------------- weight reorder: [co][ci][27] fp32 -> [t][c32][co][kb][8] bf16 ----------------
template <int CIN_T>
__global__ __launch_bounds__(256) void wreorder_k(const float* __restrict__ w,
                                                  bf16* __restrict__ wf) {
    const int NC = CIN_T / 32;
    int u = blockIdx.x * 256 + threadIdx.x;
    if (u >= 27 * NC * 128 * 4) return;
    int kb = u & 3;
    int co = (u >> 2) & 127;
    int c32 = (u >> 9) % NC;
    int t = u / (512 * NC);
    int cibase = c32 * 32 + kb * 8;
    ushort o[8];
#pragma unroll
    for (int j = 0; j < 8; ++j)
        o[j] = f2bu(w[((size_t)co * CIN_T + cibase + j) * 27 + t]);
    *(short8*)(wf + (size_t)u * 8) = *(short8*)o;
}

// ---------------- implicit-GEMM conv3d 3x3x3 via MFMA bf16 + fused GN stats ----------------
// block 512 = 8 waves (2 cog x 4 sg); wave: 64 co x 32 sp  (4 A-frags x 2 B-frags, 8 MFMA/tap)
// LDS: [kb-plane 0..3][pos 0..611] x 16B, planes 9792B apart -> <=2-way bank access
template <int CIN_T>
__global__ __launch_bounds__(512, 6) void conv3d_mfma_k(const bf16* __restrict__ x,
                                                        const bf16* __restrict__ wf,
                                                        const float* __restrict__ bias,
                                                        bf16* __restrict__ y,
                                                        float* __restrict__ gnacc) {  // [64][2]
    constexpr int NC = CIN_T / 32;
    int blk = blockIdx.x;
    int hq = blk & 7;
    int d = (blk >> 3) & 31;
    int b = blk >> 8;
    int t = threadIdx.x;
    int lane = t & 63;
    int wid = t >> 6;
    int cog = wid >> 2;  // 0..1
    int sg = wid & 3;    // 0..3
    int lr = lane & 15;
    int kb = lane >> 4;

    __shared__ __align__(16) char xs[4 * 612 * 16];  // 39168 B

    f32x4 acc[4][2];
#pragma unroll
    for (int r = 0; r < 4; ++r)
#pragma unroll
        for (int j = 0; j < 2; ++j) acc[r][j] = (f32x4){0.f, 0.f, 0.f, 0.f};

    int bbase[2];
#pragma unroll
    for (int j = 0; j < 2; ++j)
        bbase[j] = kb * 9792 + (sg * 34 + j * 16 + lr) * 16;  // hl = sg, wl = j*16+lr

    for (int cc = 0; cc < NC; ++cc) {
        __syncthreads();
        for (int e = t; e < 612 * 4; e += 512) {
            int ekb = e & 3;
            int pos = e >> 2;
            int ww = pos % 34;
            int hh = (pos / 34) % 6;
            int dd = pos / 204;
            int dz = d + dd - 1;
            int hz = hq * 4 + hh - 1;
            int wz = ww - 1;
            short8 v = {0, 0, 0, 0, 0, 0, 0, 0};
            if (dz >= 0 && dz < RES && hz >= 0 && hz < RES && wz >= 0 && wz < RES)
                v = *(const short8*)(x + ((size_t)b * R3 + dz * 1024 + hz * 32 + wz) * CIN_T + cc * 32 + ekb * 8);
            *(short8*)(xs + ekb * 9792 + pos * 16) = v;
        }
        __syncthreads();

        const short8* wfp = (const short8*)wf;
        size_t abase = ((size_t)cc * 128 + cog * 64 + lr) * 4 + kb;
#pragma unroll
        for (int dd = 0; dd < 3; ++dd)
#pragma unroll
            for (int dh = 0; dh < 3; ++dh)
#pragma unroll
                for (int dw = 0; dw < 3; ++dw) {
                    int tap = (dd * 3 + dh) * 3 + dw;
                    size_t ab = abase + (size_t)tap * NC * 512;
                    short8 a0 = wfp[ab];
                    short8 a1 = wfp[ab + 64];
                    short8 a2 = wfp[ab + 128];
                    short8 a3 = wfp[ab + 192];
                    int toff = ((dd * 6 + dh) * 34 + dw) * 16;
                    short8 b0 = *(const short8*)(xs + bbase[0] + toff);
                    short8 b1 = *(const short8*)(xs + bbase[1] + toff);
                    acc[0][0] = __builtin_amdgcn_mfma_f32_16x16x32_bf16(a0, b0, acc[0][0], 0, 0, 0);
                    acc[0][1] = __builtin_amdgcn_mfma_f32_16x16x32_bf16(a0, b1, acc[0][1], 0, 0, 0);
                    acc[1][0] = __builtin_amdgcn_mfma_f32_16x16x32_bf16(a1, b0, acc[1][0], 0, 0, 0);
                    acc[1][1] = __builtin_amdgcn_mfma_f32_16x16x32_bf16(a1, b1, acc[1][1], 0, 0, 0);
                    acc[2][0] = __builtin_amdgcn_mfma_f32_16x16x32_bf16(a2, b0, acc[2][0], 0, 0, 0);
                    acc[2][1] = __builtin_amdgcn_mfma_f32_16x16x32_bf16(a2, b1, acc[2][1], 0, 0, 0);
                    acc[3][0] = __builtin_amdgcn_mfma_f32_16x16x32_bf16(a3, b0, acc[3][0], 0, 0, 0);
                    acc[3][1] = __builtin_amdgcn_mfma_f32_16x16x32_bf16(a3, b1, acc[3][1], 0, 0, 0);
                }
    }

    // epilogue: store bf16 + per-wave GN partial stats (group g = co>>4 = cog*4 + r)
    float sred[4], ssred[4];
#pragma unroll
    for (int r = 0; r < 4; ++r) {
        int co = cog * 64 + r * 16 + kb * 4;
        float4 bv = *(const float4*)(bias + co);
        float s = 0.f, ss = 0.f;
#pragma unroll
        for (int j = 0; j < 2; ++j) {
            int sp = sg * 32 + j * 16 + lr;
            int p = d * 1024 + (hq * 4 + sg) * 32 + (sp & 31);
            float v0 = acc[r][j][0] + bv.x;
            float v1 = acc[r][j][1] + bv.y;
            float v2 = acc[r][j][2] + bv.z;
            float v3 = acc[r][j][3] + bv.w;
            ushort4 o;
            o.x = f2bu(v0); o.y = f2bu(v1); o.z = f2bu(v2); o.w = f2bu(v3);
            *(ushort4*)(y + ((size_t)b * R3 + p) * COUT + co) = o;
            s += v0 + v1 + v2 + v3;
            ss += v0 * v0 + v1 * v1 + v2 * v2 + v3 * v3;
        }
        sred[r] = s; ssred[r] = ss;
    }
#pragma unroll
    for (int m = 1; m < 64; m <<= 1) {
#pragma unroll
        for (int r = 0; r < 4; ++r) {
            sred[r] += __shfl_xor(sred[r], m, 64);
            ssred[r] += __shfl_xor(ssred[r], m, 64);
        }
    }
    if (lane == 0) {
#pragma unroll
        for (int r = 0; r < 4; ++r) {
            int bg = b * 8 + cog * 4 + r;
            atomicAdd(&gnacc[bg * 2 + 0], sred[r]);
            atomicAdd(&gnacc[bg * 2 + 1], ssred[r]);
        }
    }
}

// ---------------- GN apply + swish on channel-last bf16 (act1 only) ----------------
__global__ __launch_bounds__(256) void gn_apply_cl_k(bf16* __restrict__ x,
                                                     const float* __restrict__ gnacc,
                                                     const float* __restrict__ gamma,
                                                     const float* __restrict__ beta) {
    int u = blockIdx.x * 256 + threadIdx.x;
    int ci8 = u & 15;
    int p = (u >> 4) & (R3 - 1);
    int b = u >> 19;
    int ci = ci8 * 8;
    int bg = b * 8 + (ci8 >> 1);
    const float M = (float)(GSIZE * R3);
    float s = gnacc[bg * 2], ss = gnacc[bg * 2 + 1];
    float mean = s / M;
    float istd = rsqrtf(fmaxf(ss / M - mean * mean, 0.f) + 1e-5f);
    bf16* ptr = x + ((size_t)b * R3 + p) * COUT + ci;
    short8 v = *(const short8*)ptr;
    ushort o[8];
#pragma unroll
    for (int j = 0; j < 8; ++j) {
        float f = b2f((ushort)v[j]);
        float yv = fmaf((f - mean) * istd, gamma[ci + j], beta[ci + j]);
        o[j] = f2bu(yv / (1.f + expf(-yv)));
    }
    *(short8*)ptr = *(short8*)o;
}

// ---------------- point branch GEMM into d_out + fused GN stats ----------------
__global__ __launch_bounds__(256) void point_gemm_k(const float* __restrict__ feats,
                                                    const float* __restrict__ wp,
                                                    const float* __restrict__ bp,
                                                    float* __restrict__ pf,
                                                    float* __restrict__ gnacc) {  // [64][2]
    int blk = blockIdx.x;
    int b = blk / (NPTS / 256);
    int n = (blk % (NPTS / 256)) * 256 + threadIdx.x;
    int lane = threadIdx.x & 63;
    float f[CIN];
    const float* fp = feats + ((size_t)b * CIN) * NPTS + n;
#pragma unroll
    for (int ci = 0; ci < CIN; ++ci) f[ci] = fp[(size_t)ci * NPTS];
    float gs[8], gss[8];
#pragma unroll
    for (int g = 0; g < 8; ++g) { gs[g] = 0.f; gss[g] = 0.f; }
#pragma unroll
    for (int g = 0; g < 8; ++g) {
#pragma unroll
        for (int h = 0; h < 2; ++h) {
            int c0 = g * 16 + h * 8;
            float a[8];
#pragma unroll
            for (int k = 0; k < 8; ++k) a[k] = bp[c0 + k];
#pragma unroll
            for (int ci = 0; ci < CIN; ++ci) {
                float fv = f[ci];
#pragma unroll
                for (int k = 0; k < 8; ++k) a[k] = fmaf(wp[(size_t)(c0 + k) * CIN + ci], fv, a[k]);
            }
            size_t ob = ((size_t)b * COUT + c0) * NPTS + n;
#pragma unroll
            for (int k = 0; k < 8; ++k) {
                pf[ob + (size_t)k * NPTS] = a[k];
                gs[g] += a[k];
                gss[g] += a[k] * a[k];
            }
        }
    }
#pragma unroll
    for (int m = 1; m < 64; m <<= 1) {
#pragma unroll
        for (int g = 0; g < 8; ++g) {
            gs[g] += __shfl_xor(gs[g], m, 64);
            gss[g] += __shfl_xor(gss[g], m, 64);
        }
    }
    if (lane == 0) {
#pragma unroll
        for (int g = 0; g < 8; ++g) {
            atomicAdd(&gnacc[(b * 8 + g) * 2 + 0], gs[g]);
            atomicAdd(&gnacc[(b * 8 + g) * 2 + 1], gss[g]);
        }
    }
}

// ---------------- fuse: GN2+swish on corners, trilinear, GN-p+swish on pf, add ----------------
__global__ __launch_bounds__(256) void fuse_k(const bf16* __restrict__ vox,  // raw conv2 out [b][p][128]
                                              const float* __restrict__ nc,
                                              const float* __restrict__ gn2acc,
                                              const float* __restrict__ gnpacc,
                                              const float* __restrict__ g2g,
                                              const float* __restrict__ g2b,
                                              const float* __restrict__ gpg,
                                              const float* __restrict__ gpb,
                                              float* __restrict__ out) {
    int g = blockIdx.x * 256 + threadIdx.x;
    int b = g / NPTS, n = g % NPTS;
    const float CMAX = (float)(RES - 1) - 1e-6f;
    float cx = fminf(nc[((size_t)b * 3 + 0) * NPTS + n], CMAX);
    float cy = fminf(nc[((size_t)b * 3 + 1) * NPTS + n], CMAX);
    float cz = fminf(nc[((size_t)b * 3 + 2) * NPTS + n], CMAX);
    int ix0 = (int)cx, iy0 = (int)cy, iz0 = (int)cz;
    float fx = cx - ix0, fy = cy - iy0, fz = cz - iz0;
    int ix1 = min(ix0 + 1, RES - 1), iy1 = min(iy0 + 1, RES - 1), iz1 = min(iz0 + 1, RES - 1);
    float gx0 = 1.f - fx, gy0 = 1.f - fy, gz0 = 1.f - fz;
    float wc[8] = {gx0 * gy0 * gz0, gx0 * gy0 * fz, gx0 * fy * gz0, gx0 * fy * fz,
                   fx * gy0 * gz0,  fx * gy0 * fz,  fx * fy * gz0,  fx * fy * fz};
    int fi[8];
    fi[0] = (ix0 * RES + iy0) * RES + iz0; fi[1] = (ix0 * RES + iy0) * RES + iz1;
    fi[2] = (ix0 * RES + iy1) * RES + iz0; fi[3] = (ix0 * RES + iy1) * RES + iz1;
    fi[4] = (ix1 * RES + iy0) * RES + iz0; fi[5] = (ix1 * RES + iy0) * RES + iz1;
    fi[6] = (ix1 * RES + iy1) * RES + iz0; fi[7] = (ix1 * RES + iy1) * RES + iz1;
    const bf16* vb = vox + (size_t)b * R3 * COUT;
    float* ob = out + ((size_t)b * COUT) * NPTS + n;
    const float M2 = (float)(GSIZE * R3);
    const float Mp = (float)(GSIZE * NPTS);
    for (int o = 0; o < COUT; o += 8) {
        int bg = b * 8 + (o >> 4);
        float s2 = gn2acc[bg * 2], ss2 = gn2acc[bg * 2 + 1];
        float mean2 = s2 / M2;
        float istd2 = rsqrtf(fmaxf(ss2 / M2 - mean2 * mean2, 0.f) + 1e-5f);
        float sp = gnpacc[bg * 2], ssp = gnpacc[bg * 2 + 1];
        float meanp = sp / Mp;
        float istdp = rsqrtf(fmaxf(ssp / Mp - meanp * meanp, 0.f) + 1e-5f);
        // affine fold: vn = v*ga + gb
        float ga[8], gb[8], pa[8], pb[8];
#pragma unroll
        for (int j = 0; j < 8; ++j) {
            float gmj = g2g[o + j];
            ga[j] = istd2 * gmj;
            gb[j] = g2b[o + j] - mean2 * istd2 * gmj;
            float pmj = gpg[o + j];
            pa[j] = istdp * pmj;
            pb[j] = gpb[o + j] - meanp * istdp * pmj;
        }
        float accv[8] = {0.f, 0.f, 0.f, 0.f, 0.f, 0.f, 0.f, 0.f};
#pragma unroll
        for (int f = 0; f < 8; ++f) {
            short8 v = *(const short8*)(vb + (size_t)fi[f] * COUT + o);
            float wgt = wc[f];
#pragma unroll
            for (int j = 0; j < 8; ++j) {
                float yv = fmaf(b2f((ushort)v[j]), ga[j], gb[j]);
                float sw = yv / (1.f + expf(-yv));
                accv[j] = fmaf(wgt, sw, accv[j]);
            }
        }
#pragma unroll
        for (int j = 0; j < 8; ++j) {
            float pfv = ob[(size_t)(o + j) * NPTS];
            float yv = fmaf(pfv, pa[j], pb[j]);
            float sw = yv / (1.f + expf(-yv));
            ob[(size_t)(o + j) * NPTS] = sw + accv[j];
        }
    }
}

extern "C" void kernel_launch(void* const* d_in, const int* in_sizes, int n_in,
                              void* d_out, int out_size, void* d_ws, size_t ws_size,
                              hipStream_t stream) {
    const float* features = (const float*)d_in[0];
    const float* coords   = (const float*)d_in[1];
    const float* w1  = (const float*)d_in[3];
    const float* b1  = (const float*)d_in[4];
    const float* g1g = (const float*)d_in[5];
    const float* g1b = (const float*)d_in[6];
    const float* w2  = (const float*)d_in[7];
    const float* b2  = (const float*)d_in[8];
    const float* g2g = (const float*)d_in[9];
    const float* g2b = (const float*)d_in[10];
    const float* wp  = (const float*)d_in[11];
    const float* bp  = (const float*)d_in[12];
    const float* gpg = (const float*)d_in[13];
    const float* gpb = (const float*)d_in[14];
    float* out = (float*)d_out;

    char* ws = (char*)d_ws;
    size_t off = 0;
    bf16* act1 = (bf16*)(ws + off);          off += (size_t)BATCH * R3 * COUT * 2;  // 64MB
    bf16* act2 = (bf16*)(ws + off);          // overlays voxCL+featT
    bf16* voxCL = (bf16*)(ws + off);         off += (size_t)BATCH * R3 * CIN * 2;   // 32MB
    float* featT = (float*)(ws + off);       off += (size_t)BATCH * NPTS * CIN * 4; // 32MB
    bf16* w1f = (bf16*)(ws + off);           off += (size_t)27 * 2 * 128 * 32 * 2;
    bf16* w2f = (bf16*)(ws + off);           off += (size_t)27 * 4 * 128 * 32 * 2;
    float* ncb = (float*)(ws + off);         off += (size_t)BATCH * 3 * NPTS * 4;
    unsigned int* cnts = (unsigned int*)(ws + off);  off += (size_t)BATCH * R3 * 4;
    unsigned int* offs = (unsigned int*)(ws + off);  off += (size_t)BATCH * R3 * 4;
    int* vidx = (int*)(ws + off);            off += (size_t)BATCH * NPTS * 4;
    int* slot = (int*)(ws + off);            off += (size_t)BATCH * NPTS * 4;
    unsigned int* pidx = (unsigned int*)(ws + off);  off += (size_t)BATCH * NPTS * 4;
    unsigned int* part = (unsigned int*)(ws + off);  off += 4096;
    float* bstats = (float*)(ws + off);      off += 256;
    float* gn1acc = (float*)(ws + off);      off += 512;   // [64][2]
    float* gn2acc = (float*)(ws + off);      off += 512;
    float* gnpacc = (float*)(ws + off);      off += 512;

    hipMemsetAsync(cnts, 0, (size_t)BATCH * R3 * 4, stream);
    hipMemsetAsync(gn1acc, 0, 3 * 512, stream);

    coord_stats_k<<<BATCH, 256, 0, stream>>>(coords, bstats);
    vox_idx_k<<<BATCH * NPTS / 256, 256, 0, stream>>>(coords, bstats, ncb, vidx, slot, cnts);
    transpose_feats_k<<<BATCH * 256, 256, 0, stream>>>(features, featT);
    scan1_k<<<BATCH * R3 / 256, 256, 0, stream>>>(cnts, offs, part);
    scan2_k<<<1, 1024, 0, stream>>>(part);
    scan3_k<<<BATCH * R3 / 256, 256, 0, stream>>>(offs, part);
    scatter_pts_k<<<BATCH * NPTS / 256, 256, 0, stream>>>(vidx, slot, offs, pidx);
    gather_k<<<BATCH * R3 * 8 / 256, 256, 0, stream>>>(featT, cnts, offs, pidx, voxCL);

    wreorder_k<CIN><<<(27 * 2 * 128 * 4 + 255) / 256, 256, 0, stream>>>(w1, w1f);
    wreorder_k<COUT><<<(27 * 4 * 128 * 4 + 255) / 256, 256, 0, stream>>>(w2, w2f);

    conv3d_mfma_k<CIN><<<BATCH * 32 * 8, 512, 0, stream>>>(voxCL, w1f, b1, act1, gn1acc);
    gn_apply_cl_k<<<BATCH * R3 * 16 / 256, 256, 0, stream>>>(act1, gn1acc, g1g, g1b);

    conv3d_mfma_k<COUT><<<BATCH * 32 * 8, 512, 0, stream>>>(act1, w2f, b2, act2, gn2acc);

    point_gemm_k<<<BATCH * NPTS / 256, 256, 0, stream>>>(features, wp, bp, out, gnpacc);

    fuse_k<<<BATCH * NPTS / 256, 256, 0, stream>>>(act2, ncb, gn2acc, gnpacc,
                                                   g2g, g2b, gpg, gpb, out);
}

// Round 6
// 927.383 us; speedup vs baseline: 2.6232x; 2.6232x over previous
//
#include <hip/hip_runtime.h>
#include <hip/hip_bf16.h>
#include <cmath>

#define BATCH 8
#define CIN 64
#define COUT 128
#define NPTS 16384
#define RES 32
#define R3 32768
#define NGROUP 8
#define GSIZE 16

typedef __hip_bfloat16 bf16;
typedef __attribute__((ext_vector_type(8))) short short8;
typedef __attribute__((ext_vector_type(4))) float f32x4;

__device__ inline float b2f(ushort u) { union { float f; uint v; } x; x.v = ((uint)u) << 16; return x.f; }
__device__ inline ushort f2bu(float f) { __hip_bfloat16 h = __float2bfloat16(f); return *reinterpret_cast<ushort*>(&h); }

// ---------------- coord stats ----------------
__global__ __launch_bounds__(256) void coord_stats_k(const float* __restrict__ coords,
                                                     float* __restrict__ bstats) {
    int b = blockIdx.x;
    int t = threadIdx.x;
    __shared__ float red[256];
    __shared__ float means[3];
    for (int c = 0; c < 3; ++c) {
        float acc = 0.f;
        const float* p = coords + ((size_t)b * 3 + c) * NPTS;
        for (int n = t; n < NPTS; n += 256) acc += p[n];
        red[t] = acc; __syncthreads();
        for (int s = 128; s > 0; s >>= 1) { if (t < s) red[t] += red[t + s]; __syncthreads(); }
        if (t == 0) means[c] = red[0] * (1.f / NPTS);
        __syncthreads();
    }
    float m0 = means[0], m1 = means[1], m2 = means[2];
    const float* px = coords + ((size_t)b * 3 + 0) * NPTS;
    const float* py = coords + ((size_t)b * 3 + 1) * NPTS;
    const float* pz = coords + ((size_t)b * 3 + 2) * NPTS;
    float mx = 0.f;
    for (int n = t; n < NPTS; n += 256) {
        float dx = px[n] - m0, dy = py[n] - m1, dz = pz[n] - m2;
        mx = fmaxf(mx, sqrtf(dx * dx + dy * dy + dz * dz));
    }
    red[t] = mx; __syncthreads();
    for (int s = 128; s > 0; s >>= 1) { if (t < s) red[t] = fmaxf(red[t], red[t + s]); __syncthreads(); }
    if (t == 0) {
        bstats[b * 4 + 0] = m0; bstats[b * 4 + 1] = m1; bstats[b * 4 + 2] = m2;
        bstats[b * 4 + 3] = 1.f / (2.f * red[0]);
    }
}

// ---------------- per-point voxel index + nc + count ----------------
__global__ __launch_bounds__(256) void vox_idx_k(const float* __restrict__ coords,
                                                 const float* __restrict__ bstats,
                                                 float* __restrict__ nc,
                                                 int* __restrict__ vidx,
                                                 int* __restrict__ slot,
                                                 unsigned int* __restrict__ cnts) {
    int g = blockIdx.x * 256 + threadIdx.x;
    int b = g >> 14, n = g & (NPTS - 1);
    float m0 = bstats[b * 4 + 0], m1 = bstats[b * 4 + 1], m2 = bstats[b * 4 + 2];
    float sc = bstats[b * 4 + 3];
    float x = coords[((size_t)b * 3 + 0) * NPTS + n];
    float y = coords[((size_t)b * 3 + 1) * NPTS + n];
    float z = coords[((size_t)b * 3 + 2) * NPTS + n];
    float ncx = fminf(fmaxf(((x - m0) * sc + 0.5f) * (float)RES, 0.f), RES - 1.f);
    float ncy = fminf(fmaxf(((y - m1) * sc + 0.5f) * (float)RES, 0.f), RES - 1.f);
    float ncz = fminf(fmaxf(((z - m2) * sc + 0.5f) * (float)RES, 0.f), RES - 1.f);
    nc[((size_t)b * 3 + 0) * NPTS + n] = ncx;
    nc[((size_t)b * 3 + 1) * NPTS + n] = ncy;
    nc[((size_t)b * 3 + 2) * NPTS + n] = ncz;
    int ix = min(max((int)rintf(ncx), 0), RES - 1);  // rintf = half-even = jnp.round
    int iy = min(max((int)rintf(ncy), 0), RES - 1);
    int iz = min(max((int)rintf(ncz), 0), RES - 1);
    int v = b * R3 + (ix * RES + iy) * RES + iz;
    vidx[g] = v;
    slot[g] = (int)atomicAdd(&cnts[v], 1u);
}

// ---------------- feature transpose: [b][64][N] fp32 -> [b][n][64] fp32 ----------------
__global__ __launch_bounds__(256) void transpose_feats_k(const float* __restrict__ feats,
                                                         float* __restrict__ featT) {
    int blk = blockIdx.x;
    int b = blk >> 8, ntile = blk & 255;
    int t = threadIdx.x;
    __shared__ float lds[64][65];
    for (int e = t; e < 64 * 64; e += 256) {
        int c = e >> 6, n = e & 63;
        lds[c][n] = feats[((size_t)b * CIN + c) * NPTS + ntile * 64 + n];
    }
    __syncthreads();
    for (int e = t; e < 64 * 64; e += 256) {
        int n = e >> 6, c = e & 63;
        featT[(((size_t)b << 14) + ntile * 64 + n) * CIN + c] = lds[c][n];
    }
}

// ---------------- scan ----------------
__global__ __launch_bounds__(256) void scan1_k(const unsigned int* __restrict__ cnts,
                                               unsigned int* __restrict__ offs,
                                               unsigned int* __restrict__ part) {
    int t = threadIdx.x;
    int g = blockIdx.x * 256 + t;
    unsigned int v = cnts[g];
    __shared__ unsigned int s[256];
    s[t] = v; __syncthreads();
    for (int d = 1; d < 256; d <<= 1) {
        unsigned int x = (t >= d) ? s[t - d] : 0u;
        __syncthreads();
        s[t] += x;
        __syncthreads();
    }
    offs[g] = s[t] - v;
    if (t == 255) part[blockIdx.x] = s[255];
}

__global__ __launch_bounds__(1024) void scan2_k(unsigned int* __restrict__ part) {
    int t = threadIdx.x;
    unsigned int v = part[t];
    __shared__ unsigned int s[1024];
    s[t] = v; __syncthreads();
    for (int d = 1; d < 1024; d <<= 1) {
        unsigned int x = (t >= d) ? s[t - d] : 0u;
        __syncthreads();
        s[t] += x;
        __syncthreads();
    }
    part[t] = s[t] - v;
}

__global__ __launch_bounds__(256) void scan3_k(unsigned int* __restrict__ offs,
                                               const unsigned int* __restrict__ part) {
    int g = blockIdx.x * 256 + threadIdx.x;
    offs[g] += part[blockIdx.x];
}

// ---------------- scatter point ids into CSR ----------------
__global__ __launch_bounds__(256) void scatter_pts_k(const int* __restrict__ vidx,
                                                     const int* __restrict__ slot,
                                                     const unsigned int* __restrict__ offs,
                                                     unsigned int* __restrict__ pidx) {
    int g = blockIdx.x * 256 + threadIdx.x;
    int n = g & (NPTS - 1);
    int v = vidx[g];
    pidx[offs[v] + slot[g]] = (unsigned int)n;
}

// ---------------- gather: CSR mean -> bf16 channel-last vox ----------------
__global__ __launch_bounds__(256) void gather_k(const float* __restrict__ featT,
                                                const unsigned int* __restrict__ cnts,
                                                const unsigned int* __restrict__ offs,
                                                const unsigned int* __restrict__ pidx,
                                                bf16* __restrict__ voxCL) {
    int u = blockIdx.x * 256 + threadIdx.x;
    int v = u >> 3;
    int l8 = u & 7;
    int b = v >> 15;
    unsigned int cnt = cnts[v];
    unsigned int off = offs[v];
    float acc[8] = {0.f, 0.f, 0.f, 0.f, 0.f, 0.f, 0.f, 0.f};
    for (unsigned int i = 0; i < cnt; ++i) {
        unsigned int n = pidx[off + i];
        const float4* fp = (const float4*)(featT + (((size_t)b << 14) + n) * CIN + l8 * 8);
        float4 f0 = fp[0], f1 = fp[1];
        acc[0] += f0.x; acc[1] += f0.y; acc[2] += f0.z; acc[3] += f0.w;
        acc[4] += f1.x; acc[5] += f1.y; acc[6] += f1.z; acc[7] += f1.w;
    }
    float inv = 1.f / fmaxf((float)cnt, 1.f);
    ushort o[8];
#pragma unroll
    for (int j = 0; j < 8; ++j) o[j] = f2bu(acc[j] * inv);
    *(short8*)(voxCL + (size_t)v * CIN + l8 * 8) = *(short8*)o;
}

// ---------------- weight reorder: [co][ci][27] fp32 -> [t][c32][co][kb][8] bf16 ----------------
template <int CIN_T>
__global__ __launch_bounds__(256) void wreorder_k(const float* __restrict__ w,
                                                  bf16* __restrict__ wf) {
    const int NC = CIN_T / 32;
    int u = blockIdx.x * 256 + threadIdx.x;
    if (u >= 27 * NC * 128 * 4) return;
    int kb = u & 3;
    int co = (u >> 2) & 127;
    int c32 = (u >> 9) % NC;
    int t = u / (512 * NC);
    int cibase = c32 * 32 + kb * 8;
    ushort o[8];
#pragma unroll
    for (int j = 0; j < 8; ++j)
        o[j] = f2bu(w[((size_t)co * CIN_T + cibase + j) * 27 + t]);
    *(short8*)(wf + (size_t)u * 8) = *(short8*)o;
}

// ---------------- implicit-GEMM conv3d 3x3x3 via MFMA bf16 (R4-proven structure) ----------------
// grid: (b, d, hq) ; block 512 = 8 waves (4 co-groups x 2 spatial-groups)
// out tile: 128 co x (4 h-rows x 32 w) = 128 sp, channel-last bf16
// + fused GN partial stats: wave shfl reduce -> LDS pre-reduce -> 16 global atomics/block
template <int CIN_T>
__global__ __launch_bounds__(512, 2) void conv3d_mfma_k(const bf16* __restrict__ x,  // [b][p][CIN_T]
                                                        const bf16* __restrict__ wf, // [27][NC][128][4][8]
                                                        const float* __restrict__ bias,
                                                        bf16* __restrict__ y,        // [b][p][128]
                                                        float* __restrict__ gnacc) { // [64][2]
    constexpr int NC = CIN_T / 32;
    int blk = blockIdx.x;
    int hq = blk & 7;
    int d = (blk >> 3) & 31;
    int b = blk >> 8;
    int t = threadIdx.x;
    int lane = t & 63;
    int wid = t >> 6;
    int cog = wid >> 1;  // 0..3
    int sg = wid & 1;    // 0..1
    int lr = lane & 15;
    int kb = lane >> 4;

    __shared__ __align__(16) char xs[3 * 6 * 34 * 80];  // 48960 B
    __shared__ float gred[8][2];
    if (t < 16) gred[t >> 1][t & 1] = 0.f;

    f32x4 acc[2][4];
#pragma unroll
    for (int r = 0; r < 2; ++r)
#pragma unroll
        for (int j = 0; j < 4; ++j) acc[r][j] = (f32x4){0.f, 0.f, 0.f, 0.f};

    int bbase[4];
#pragma unroll
    for (int j = 0; j < 4; ++j) {
        int sp = sg * 64 + j * 16 + lr;
        int hl = sp >> 5, wl = sp & 31;
        bbase[j] = (hl * 34 + wl) * 80 + kb * 16;
    }

    for (int cc = 0; cc < NC; ++cc) {
        __syncthreads();
        for (int e = t; e < 612 * 4; e += 512) {
            int ekb = e & 3;
            int pos = e >> 2;
            int ww = pos % 34;
            int hh = (pos / 34) % 6;
            int dd = pos / 204;
            int dz = d + dd - 1;
            int hz = hq * 4 + hh - 1;
            int wz = ww - 1;
            short8 v = {0, 0, 0, 0, 0, 0, 0, 0};
            if (dz >= 0 && dz < RES && hz >= 0 && hz < RES && wz >= 0 && wz < RES)
                v = *(const short8*)(x + ((size_t)b * R3 + dz * 1024 + hz * 32 + wz) * CIN_T + cc * 32 + ekb * 8);
            *(short8*)(xs + pos * 80 + ekb * 16) = v;
        }
        __syncthreads();

        const short8* wfp = (const short8*)wf;
        size_t abase = ((size_t)cc * 128 + cog * 32 + lr) * 4 + kb;
#pragma unroll
        for (int dd = 0; dd < 3; ++dd)
#pragma unroll
            for (int dh = 0; dh < 3; ++dh)
#pragma unroll
                for (int dw = 0; dw < 3; ++dw) {
                    int tap = (dd * 3 + dh) * 3 + dw;
                    short8 a0 = wfp[abase + (size_t)tap * NC * 512];
                    short8 a1 = wfp[abase + (size_t)tap * NC * 512 + 64];
                    int toff = ((dd * 6 + dh) * 34 + dw) * 80;
                    short8 bb[4];
#pragma unroll
                    for (int j = 0; j < 4; ++j)
                        bb[j] = *(const short8*)(xs + bbase[j] + toff);
#pragma unroll
                    for (int j = 0; j < 4; ++j) {
                        acc[0][j] = __builtin_amdgcn_mfma_f32_16x16x32_bf16(a0, bb[j], acc[0][j], 0, 0, 0);
                        acc[1][j] = __builtin_amdgcn_mfma_f32_16x16x32_bf16(a1, bb[j], acc[1][j], 0, 0, 0);
                    }
                }
    }

    // epilogue: store bf16 + per-wave GN partial stats (group g = co>>4 = cog*2 + r)
    float sred[2], ssred[2];
#pragma unroll
    for (int r = 0; r < 2; ++r) {
        int co = cog * 32 + r * 16 + kb * 4;
        float4 bv = *(const float4*)(bias + co);
        float s = 0.f, ss = 0.f;
#pragma unroll
        for (int j = 0; j < 4; ++j) {
            int sp = sg * 64 + j * 16 + lr;
            int p = d * 1024 + (hq * 4 + (sp >> 5)) * 32 + (sp & 31);
            float v0 = acc[r][j][0] + bv.x;
            float v1 = acc[r][j][1] + bv.y;
            float v2 = acc[r][j][2] + bv.z;
            float v3 = acc[r][j][3] + bv.w;
            ushort4 o;
            o.x = f2bu(v0); o.y = f2bu(v1); o.z = f2bu(v2); o.w = f2bu(v3);
            *(ushort4*)(y + ((size_t)b * R3 + p) * COUT + co) = o;
            s += v0 + v1 + v2 + v3;
            ss += v0 * v0 + v1 * v1 + v2 * v2 + v3 * v3;
        }
        sred[r] = s; ssred[r] = ss;
    }
#pragma unroll
    for (int m = 1; m < 64; m <<= 1) {
#pragma unroll
        for (int r = 0; r < 2; ++r) {
            sred[r] += __shfl_xor(sred[r], m, 64);
            ssred[r] += __shfl_xor(ssred[r], m, 64);
        }
    }
    if (lane == 0) {
#pragma unroll
        for (int r = 0; r < 2; ++r) {
            atomicAdd(&gred[cog * 2 + r][0], sred[r]);
            atomicAdd(&gred[cog * 2 + r][1], ssred[r]);
        }
    }
    __syncthreads();
    if (t < 16) atomicAdd(&gnacc[(b * 8 + (t >> 1)) * 2 + (t & 1)], gred[t >> 1][t & 1]);
}

// ---------------- GN apply + swish on channel-last bf16 (act1 only) ----------------
__global__ __launch_bounds__(256) void gn_apply_cl_k(bf16* __restrict__ x,
                                                     const float* __restrict__ gnacc,
                                                     const float* __restrict__ gamma,
                                                     const float* __restrict__ beta) {
    int u = blockIdx.x * 256 + threadIdx.x;
    int ci8 = u & 15;
    int p = (u >> 4) & (R3 - 1);
    int b = u >> 19;
    int ci = ci8 * 8;
    int bg = b * 8 + (ci8 >> 1);
    const float M = (float)(GSIZE * R3);
    float s = gnacc[bg * 2], ss = gnacc[bg * 2 + 1];
    float mean = s / M;
    float istd = rsqrtf(fmaxf(ss / M - mean * mean, 0.f) + 1e-5f);
    bf16* ptr = x + ((size_t)b * R3 + p) * COUT + ci;
    short8 v = *(const short8*)ptr;
    ushort o[8];
#pragma unroll
    for (int j = 0; j < 8; ++j) {
        float f = b2f((ushort)v[j]);
        float yv = fmaf((f - mean) * istd, gamma[ci + j], beta[ci + j]);
        o[j] = f2bu(yv / (1.f + expf(-yv)));
    }
    *(short8*)ptr = *(short8*)o;
}

// ---------------- point branch GEMM into d_out + fused GN stats ----------------
__global__ __launch_bounds__(256) void point_gemm_k(const float* __restrict__ feats,
                                                    const float* __restrict__ wp,
                                                    const float* __restrict__ bp,
                                                    float* __restrict__ pf,
                                                    float* __restrict__ gnacc) {  // [64][2]
    int blk = blockIdx.x;
    int b = blk / (NPTS / 256);
    int n = (blk % (NPTS / 256)) * 256 + threadIdx.x;
    int lane = threadIdx.x & 63;
    float f[CIN];
    const float* fp = feats + ((size_t)b * CIN) * NPTS + n;
#pragma unroll
    for (int ci = 0; ci < CIN; ++ci) f[ci] = fp[(size_t)ci * NPTS];
    float gs[8], gss[8];
#pragma unroll
    for (int g = 0; g < 8; ++g) { gs[g] = 0.f; gss[g] = 0.f; }
#pragma unroll
    for (int g = 0; g < 8; ++g) {
#pragma unroll
        for (int h = 0; h < 2; ++h) {
            int c0 = g * 16 + h * 8;
            float a[8];
#pragma unroll
            for (int k = 0; k < 8; ++k) a[k] = bp[c0 + k];
#pragma unroll
            for (int ci = 0; ci < CIN; ++ci) {
                float fv = f[ci];
#pragma unroll
                for (int k = 0; k < 8; ++k) a[k] = fmaf(wp[(size_t)(c0 + k) * CIN + ci], fv, a[k]);
            }
            size_t ob = ((size_t)b * COUT + c0) * NPTS + n;
#pragma unroll
            for (int k = 0; k < 8; ++k) {
                pf[ob + (size_t)k * NPTS] = a[k];
                gs[g] += a[k];
                gss[g] += a[k] * a[k];
            }
        }
    }
#pragma unroll
    for (int m = 1; m < 64; m <<= 1) {
#pragma unroll
        for (int g = 0; g < 8; ++g) {
            gs[g] += __shfl_xor(gs[g], m, 64);
            gss[g] += __shfl_xor(gss[g], m, 64);
        }
    }
    if (lane == 0) {
#pragma unroll
        for (int g = 0; g < 8; ++g) {
            atomicAdd(&gnacc[(b * 8 + g) * 2 + 0], gs[g]);
            atomicAdd(&gnacc[(b * 8 + g) * 2 + 1], gss[g]);
        }
    }
}

// ---------------- fuse: GN2+swish on corners, trilinear, GN-p+swish on pf, add ----------------
__global__ __launch_bounds__(256) void fuse_k(const bf16* __restrict__ vox,  // raw conv2 out [b][p][128]
                                              const float* __restrict__ nc,
                                              const float* __restrict__ gn2acc,
                                              const float* __restrict__ gnpacc,
                                              const float* __restrict__ g2g,
                                              const float* __restrict__ g2b,
                                              const float* __restrict__ gpg,
                                              const float* __restrict__ gpb,
                                              float* __restrict__ out) {
    int g = blockIdx.x * 256 + threadIdx.x;
    int b = g / NPTS, n = g % NPTS;
    const float CMAX = (float)(RES - 1) - 1e-6f;
    float cx = fminf(nc[((size_t)b * 3 + 0) * NPTS + n], CMAX);
    float cy = fminf(nc[((size_t)b * 3 + 1) * NPTS + n], CMAX);
    float cz = fminf(nc[((size_t)b * 3 + 2) * NPTS + n], CMAX);
    int ix0 = (int)cx, iy0 = (int)cy, iz0 = (int)cz;
    float fx = cx - ix0, fy = cy - iy0, fz = cz - iz0;
    int ix1 = min(ix0 + 1, RES - 1), iy1 = min(iy0 + 1, RES - 1), iz1 = min(iz0 + 1, RES - 1);
    float gx0 = 1.f - fx, gy0 = 1.f - fy, gz0 = 1.f - fz;
    float wc[8] = {gx0 * gy0 * gz0, gx0 * gy0 * fz, gx0 * fy * gz0, gx0 * fy * fz,
                   fx * gy0 * gz0,  fx * gy0 * fz,  fx * fy * gz0,  fx * fy * fz};
    int fi[8];
    fi[0] = (ix0 * RES + iy0) * RES + iz0; fi[1] = (ix0 * RES + iy0) * RES + iz1;
    fi[2] = (ix0 * RES + iy1) * RES + iz0; fi[3] = (ix0 * RES + iy1) * RES + iz1;
    fi[4] = (ix1 * RES + iy0) * RES + iz0; fi[5] = (ix1 * RES + iy0) * RES + iz1;
    fi[6] = (ix1 * RES + iy1) * RES + iz0; fi[7] = (ix1 * RES + iy1) * RES + iz1;
    const bf16* vb = vox + (size_t)b * R3 * COUT;
    float* ob = out + ((size_t)b * COUT) * NPTS + n;
    const float M2 = (float)(GSIZE * R3);
    const float Mp = (float)(GSIZE * NPTS);
    for (int o = 0; o < COUT; o += 8) {
        int bg = b * 8 + (o >> 4);
        float s2 = gn2acc[bg * 2], ss2 = gn2acc[bg * 2 + 1];
        float mean2 = s2 / M2;
        float istd2 = rsqrtf(fmaxf(ss2 / M2 - mean2 * mean2, 0.f) + 1e-5f);
        float sp = gnpacc[bg * 2], ssp = gnpacc[bg * 2 + 1];
        float meanp = sp / Mp;
        float istdp = rsqrtf(fmaxf(ssp / Mp - meanp * meanp, 0.f) + 1e-5f);
        float ga[8], gb[8], pa[8], pb[8];
#pragma unroll
        for (int j = 0; j < 8; ++j) {
            float gmj = g2g[o + j];
            ga[j] = istd2 * gmj;
            gb[j] = g2b[o + j] - mean2 * istd2 * gmj;
            float pmj = gpg[o + j];
            pa[j] = istdp * pmj;
            pb[j] = gpb[o + j] - meanp * istdp * pmj;
        }
        float accv[8] = {0.f, 0.f, 0.f, 0.f, 0.f, 0.f, 0.f, 0.f};
#pragma unroll
        for (int f = 0; f < 8; ++f) {
            short8 v = *(const short8*)(vb + (size_t)fi[f] * COUT + o);
            float wgt = wc[f];
#pragma unroll
            for (int j = 0; j < 8; ++j) {
                float yv = fmaf(b2f((ushort)v[j]), ga[j], gb[j]);
                float sw = yv / (1.f + expf(-yv));
                accv[j] = fmaf(wgt, sw, accv[j]);
            }
        }
#pragma unroll
        for (int j = 0; j < 8; ++j) {
            float pfv = ob[(size_t)(o + j) * NPTS];
            float yv = fmaf(pfv, pa[j], pb[j]);
            float sw = yv / (1.f + expf(-yv));
            ob[(size_t)(o + j) * NPTS] = sw + accv[j];
        }
    }
}

extern "C" void kernel_launch(void* const* d_in, const int* in_sizes, int n_in,
                              void* d_out, int out_size, void* d_ws, size_t ws_size,
                              hipStream_t stream) {
    const float* features = (const float*)d_in[0];
    const float* coords   = (const float*)d_in[1];
    const float* w1  = (const float*)d_in[3];
    const float* b1  = (const float*)d_in[4];
    const float* g1g = (const float*)d_in[5];
    const float* g1b = (const float*)d_in[6];
    const float* w2  = (const float*)d_in[7];
    const float* b2  = (const float*)d_in[8];
    const float* g2g = (const float*)d_in[9];
    const float* g2b = (const float*)d_in[10];
    const float* wp  = (const float*)d_in[11];
    const float* bp  = (const float*)d_in[12];
    const float* gpg = (const float*)d_in[13];
    const float* gpb = (const float*)d_in[14];
    float* out = (float*)d_out;

    char* ws = (char*)d_ws;
    size_t off = 0;
    bf16* act1 = (bf16*)(ws + off);          off += (size_t)BATCH * R3 * COUT * 2;  // 64MB
    bf16* act2 = (bf16*)(ws + off);          // overlays voxCL+featT
    bf16* voxCL = (bf16*)(ws + off);         off += (size_t)BATCH * R3 * CIN * 2;   // 32MB
    float* featT = (float*)(ws + off);       off += (size_t)BATCH * NPTS * CIN * 4; // 32MB
    bf16* w1f = (bf16*)(ws + off);           off += (size_t)27 * 2 * 128 * 32 * 2;
    bf16* w2f = (bf16*)(ws + off);           off += (size_t)27 * 4 * 128 * 32 * 2;
    float* ncb = (float*)(ws + off);         off += (size_t)BATCH * 3 * NPTS * 4;
    unsigned int* cnts = (unsigned int*)(ws + off);  off += (size_t)BATCH * R3 * 4;
    unsigned int* offs = (unsigned int*)(ws + off);  off += (size_t)BATCH * R3 * 4;
    int* vidx = (int*)(ws + off);            off += (size_t)BATCH * NPTS * 4;
    int* slot = (int*)(ws + off);            off += (size_t)BATCH * NPTS * 4;
    unsigned int* pidx = (unsigned int*)(ws + off);  off += (size_t)BATCH * NPTS * 4;
    unsigned int* part = (unsigned int*)(ws + off);  off += 4096;
    float* bstats = (float*)(ws + off);      off += 256;
    float* gn1acc = (float*)(ws + off);      off += 512;   // [64][2]
    float* gn2acc = (float*)(ws + off);      off += 512;
    float* gnpacc = (float*)(ws + off);      off += 512;

    hipMemsetAsync(cnts, 0, (size_t)BATCH * R3 * 4, stream);
    hipMemsetAsync(gn1acc, 0, 3 * 512, stream);

    coord_stats_k<<<BATCH, 256, 0, stream>>>(coords, bstats);
    vox_idx_k<<<BATCH * NPTS / 256, 256, 0, stream>>>(coords, bstats, ncb, vidx, slot, cnts);
    transpose_feats_k<<<BATCH * 256, 256, 0, stream>>>(features, featT);
    scan1_k<<<BATCH * R3 / 256, 256, 0, stream>>>(cnts, offs, part);
    scan2_k<<<1, 1024, 0, stream>>>(part);
    scan3_k<<<BATCH * R3 / 256, 256, 0, stream>>>(offs, part);
    scatter_pts_k<<<BATCH * NPTS / 256, 256, 0, stream>>>(vidx, slot, offs, pidx);
    gather_k<<<BATCH * R3 * 8 / 256, 256, 0, stream>>>(featT, cnts, offs, pidx, voxCL);

    wreorder_k<CIN><<<(27 * 2 * 128 * 4 + 255) / 256, 256, 0, stream>>>(w1, w1f);
    wreorder_k<COUT><<<(27 * 4 * 128 * 4 + 255) / 256, 256, 0, stream>>>(w2, w2f);

    conv3d_mfma_k<CIN><<<BATCH * 32 * 8, 512, 0, stream>>>(voxCL, w1f, b1, act1, gn1acc);
    gn_apply_cl_k<<<BATCH * R3 * 16 / 256, 256, 0, stream>>>(act1, gn1acc, g1g, g1b);

    conv3d_mfma_k<COUT><<<BATCH * 32 * 8, 512, 0, stream>>>(act1, w2f, b2, act2, gn2acc);

    point_gemm_k<<<BATCH * NPTS / 256, 256, 0, stream>>>(features, wp, bp, out, gnpacc);

    fuse_k<<<BATCH * NPTS / 256, 256, 0, stream>>>(act2, ncb, gn2acc, gnpacc,
                                                   g2g, g2b, gpg, gpb, out);
}